// Round 4
// baseline (738.574 us; speedup 1.0000x reference)
//
#include <hip/hip_runtime.h>
#include <hip/hip_bf16.h>
#include <math.h>

#define SEQ 64
#define IN_DIM 16384
#define H_DIM 1024
#define G4 4096   // 4*H
#define BATCH 40
#define NB_SCAN 64
#define NT_SCAN 1024

typedef short bf16x8 __attribute__((ext_vector_type(8)));   // 8 bf16 bit-patterns (4 VGPRs)
typedef float f32x4 __attribute__((ext_vector_type(4)));
typedef unsigned int uvec4 __attribute__((ext_vector_type(4)));
typedef unsigned int uvec2 __attribute__((ext_vector_type(2)));

// ---------------- ws layout (floats) ----------------
// [0 .. 256)      flags: u32 flags[64] (monotone per-block step counters)
// OFF_AH          a_hi : [64][16384] bf16 bits (512K float slots)
// OFF_AL          a_lo : [64][16384] bf16 bits
// OFF_XW          xw   : [64][4096]
// OFF_HS          hs_c : [64][1024]  (also the per-step h exchange buffer)
// OFF_PART        part : [KS][64][4096]
#define OFF_AH   256
#define OFF_AL   (OFF_AH + (size_t)SEQ * IN_DIM / 2)
#define OFF_XW   (OFF_AL + (size_t)SEQ * IN_DIM / 2)
#define OFF_HS   (OFF_XW + (size_t)SEQ * G4)
#define OFF_PART (OFF_HS + (size_t)SEQ * H_DIM)

// ---------------- zero the flag words ----------------
__global__ void zero_bar(unsigned* bar) { bar[threadIdx.x] = 0u; }

// ---------------- features fp32 -> bf16 hi/lo (lo = exact residual) ----------------
__global__ __launch_bounds__(256) void convert_a(const float* __restrict__ f,
                                                 unsigned* __restrict__ a_hi,
                                                 unsigned* __restrict__ a_lo) {
    const int i = blockIdx.x * 256 + threadIdx.x;          // float4 index
    uvec4 u = ((const uvec4*)f)[i];
    unsigned h0 = (u.x >> 16) | (u.y & 0xffff0000u);
    unsigned h1 = (u.z >> 16) | (u.w & 0xffff0000u);
    float l0 = __uint_as_float(u.x) - __uint_as_float(u.x & 0xffff0000u);
    float l1 = __uint_as_float(u.y) - __uint_as_float(u.y & 0xffff0000u);
    float l2 = __uint_as_float(u.z) - __uint_as_float(u.z & 0xffff0000u);
    float l3 = __uint_as_float(u.w) - __uint_as_float(u.w & 0xffff0000u);
    unsigned q0 = (__float_as_uint(l0) >> 16) | (__float_as_uint(l1) & 0xffff0000u);
    unsigned q1 = (__float_as_uint(l2) >> 16) | (__float_as_uint(l3) & 0xffff0000u);
    uvec2 hv; hv.x = h0; hv.y = h1;
    uvec2 lv; lv.x = q0; lv.y = q1;
    ((uvec2*)a_hi)[i] = hv;
    ((uvec2*)a_lo)[i] = lv;
}

// ---------------- split-bf16 MFMA GEMM: part[kz][t][j] = sum_k A[t][k]*w_ih[j][k] ----------------
// Block: 256 thr = 4 waves; N-tile 64 (wave w owns 16 j), M = all 64 t, K-chunk kspan.
// B frag (w_ih, [j][k] row-major): lane holds 8 consecutive k of col j0+(l&15) at k0+(l>>4)*8.
// A frag (features bf16 hi/lo):    lane holds 8 consecutive k of row t0+(l&15).
// 3-term product: Ahi*Bhi + Alo*Bhi + Ahi*Blo accumulated in f32.
__global__ __launch_bounds__(256, 2) void gemm_mfma(const float* __restrict__ w_ih,
                                                    const unsigned* __restrict__ a_hi,
                                                    const unsigned* __restrict__ a_lo,
                                                    float* __restrict__ part, int kspan) {
    const int tid = threadIdx.x;
    const int wv   = tid >> 6;
    const int lane = tid & 63;
    const int col  = lane & 15;
    const int kg   = lane >> 4;
    const int jbase = blockIdx.x * 64 + wv * 16 + col;
    const int k0base = blockIdx.y * kspan;

    const float* wrow = w_ih + (size_t)jbase * IN_DIM;

    f32x4 acc[4] = {};   // t0 = 0,16,32,48

    for (int k0 = k0base; k0 < k0base + kspan; k0 += 32) {
        const int kf = k0 + kg * 8;
        // ---- B: 8 fp32 -> hi/lo bf16x8
        uvec4 u0 = *(const uvec4*)(wrow + kf);
        uvec4 u1 = *(const uvec4*)(wrow + kf + 4);
        uvec4 hb, lb;
        hb.x = (u0.x >> 16) | (u0.y & 0xffff0000u);
        hb.y = (u0.z >> 16) | (u0.w & 0xffff0000u);
        hb.z = (u1.x >> 16) | (u1.y & 0xffff0000u);
        hb.w = (u1.z >> 16) | (u1.w & 0xffff0000u);
        float f0 = __uint_as_float(u0.x) - __uint_as_float(u0.x & 0xffff0000u);
        float f1 = __uint_as_float(u0.y) - __uint_as_float(u0.y & 0xffff0000u);
        float f2 = __uint_as_float(u0.z) - __uint_as_float(u0.z & 0xffff0000u);
        float f3 = __uint_as_float(u0.w) - __uint_as_float(u0.w & 0xffff0000u);
        float f4 = __uint_as_float(u1.x) - __uint_as_float(u1.x & 0xffff0000u);
        float f5 = __uint_as_float(u1.y) - __uint_as_float(u1.y & 0xffff0000u);
        float f6 = __uint_as_float(u1.z) - __uint_as_float(u1.z & 0xffff0000u);
        float f7 = __uint_as_float(u1.w) - __uint_as_float(u1.w & 0xffff0000u);
        lb.x = (__float_as_uint(f0) >> 16) | (__float_as_uint(f1) & 0xffff0000u);
        lb.y = (__float_as_uint(f2) >> 16) | (__float_as_uint(f3) & 0xffff0000u);
        lb.z = (__float_as_uint(f4) >> 16) | (__float_as_uint(f5) & 0xffff0000u);
        lb.w = (__float_as_uint(f6) >> 16) | (__float_as_uint(f7) & 0xffff0000u);
        bf16x8 bhi = __builtin_bit_cast(bf16x8, hb);
        bf16x8 blo = __builtin_bit_cast(bf16x8, lb);

#pragma unroll
        for (int i = 0; i < 4; ++i) {
            const size_t aidx = (size_t)(i * 16 + col) * (IN_DIM / 2) + (kf >> 1);  // u32 units
            uvec4 ah = *(const uvec4*)(a_hi + aidx);
            uvec4 al = *(const uvec4*)(a_lo + aidx);
            bf16x8 ahv = __builtin_bit_cast(bf16x8, ah);
            bf16x8 alv = __builtin_bit_cast(bf16x8, al);
            acc[i] = __builtin_amdgcn_mfma_f32_16x16x32_bf16(ahv, bhi, acc[i], 0, 0, 0);
            acc[i] = __builtin_amdgcn_mfma_f32_16x16x32_bf16(alv, bhi, acc[i], 0, 0, 0);
            acc[i] = __builtin_amdgcn_mfma_f32_16x16x32_bf16(ahv, blo, acc[i], 0, 0, 0);
        }
    }
    // D layout: row = t0 + kg*4 + r, col = jbase
    float* pb = part + (size_t)blockIdx.y * (SEQ * G4);
#pragma unroll
    for (int i = 0; i < 4; ++i)
#pragma unroll
        for (int r = 0; r < 4; ++r) {
            const int trow = i * 16 + kg * 4 + r;
            pb[(size_t)trow * G4 + jbase] = acc[i][r];
        }
}

// ---------------- reduce partials + bias -> xw ----------------
__global__ __launch_bounds__(256) void reduce_xw(const float* __restrict__ part,
                                                 const float* __restrict__ b_ih,
                                                 const float* __restrict__ b_hh,
                                                 float* __restrict__ xw, int KS) {
    const int idx = blockIdx.x * 256 + threadIdx.x;  // t*4096 + j
    const int j = idx & (G4 - 1);
    float s = b_ih[j] + b_hh[j];
    for (int ks = 0; ks < KS; ++ks) s += part[(size_t)ks * (SEQ * G4) + idx];
    xw[idx] = s;
}

// ---------------- persistent LSTM scan (B collapsed to 1) ----------------
// 64 blocks x 1024 thr. Block b owns h[b*16..b*16+16). Per-step h exchange goes
// through hs_c[t][*] (write-once slots -> race-free with one barrier/step).
// Barrier: per-block flag word (no serialized RMW); wave 0 polls all 64 flags.
__global__ __launch_bounds__(NT_SCAN, 1) void lstm_scan(const float* __restrict__ xw,
                                                        const float* __restrict__ w_hh,
                                                        float* __restrict__ hs_c,
                                                        unsigned* __restrict__ bar) {
    const int tid = threadIdx.x;
    const int b = blockIdx.x;
    const int r = tid & 63;      // gate-row 0..63
    const int q = tid >> 6;      // k-chunk 0..15
    const int g = r >> 4;
    const int jl = r & 15;
    const size_t grow = (size_t)g * H_DIM + (size_t)b * 16 + jl;

    float4 w[16];
    {
        const float4* wp = (const float4*)(w_hh + grow * H_DIM + q * 64);
#pragma unroll
        for (int m = 0; m < 16; ++m) w[m] = wp[m];
    }
#pragma unroll
    for (int m = 0; m < 16; ++m)
        asm volatile("" : "+v"(w[m].x), "+v"(w[m].y), "+v"(w[m].z), "+v"(w[m].w));

    __shared__ float h_lds[H_DIM];
    __shared__ float red[64][17];
    __shared__ float gate_lds[64];

    float c_reg = 0.f;   // live on tid<16

    for (int t = 0; t < SEQ; ++t) {
        float xwv = 0.f;
        if (tid < 64)  // prefetch gate bias row (no h dependency)
            xwv = xw[(size_t)t * G4 + (size_t)(tid >> 4) * H_DIM + b * 16 + (tid & 15)];
        float acc = 0.f;
        if (t > 0) {
            h_lds[tid] = __hip_atomic_load(hs_c + (size_t)(t - 1) * H_DIM + tid,
                                           __ATOMIC_RELAXED, __HIP_MEMORY_SCOPE_AGENT);
            __syncthreads();
#pragma unroll
            for (int m = 0; m < 16; ++m) {
                float4 h4 = *(const float4*)&h_lds[q * 64 + m * 4];
                acc += w[m].x * h4.x + w[m].y * h4.y + w[m].z * h4.z + w[m].w * h4.w;
            }
        }
        red[r][q] = acc;
        __syncthreads();
        if (tid < 64) {
            float s = 0.f;
#pragma unroll
            for (int qq = 0; qq < 16; ++qq) s += red[tid][qq];
            gate_lds[tid] = xwv + s;
        }
        __syncthreads();
        if (tid < 16) {
            float iv = gate_lds[tid];
            float fv = gate_lds[16 + tid];
            float gv = gate_lds[32 + tid];
            float ov = gate_lds[48 + tid];
            iv = 1.f / (1.f + expf(-iv));
            fv = 1.f / (1.f + expf(-fv));
            gv = tanhf(gv);
            ov = 1.f / (1.f + expf(-ov));
            c_reg = fv * c_reg + iv * gv;
            float hv = ov * tanhf(c_reg);
            __hip_atomic_store(hs_c + (size_t)t * H_DIM + b * 16 + tid, hv,
                               __ATOMIC_RELAXED, __HIP_MEMORY_SCOPE_AGENT);
        }
        if (t < SEQ - 1) {
            // wave 0's h stores ACKed at the coherence point, then publish flag
            asm volatile("s_waitcnt vmcnt(0)" ::: "memory");
            if (tid == 0)
                __hip_atomic_store(bar + b, (unsigned)t + 1u,
                                   __ATOMIC_RELAXED, __HIP_MEMORY_SCOPE_AGENT);
            if (tid < 64) {
                const unsigned target = (unsigned)t + 1u;
                unsigned v = __hip_atomic_load(bar + tid, __ATOMIC_RELAXED,
                                               __HIP_MEMORY_SCOPE_AGENT);
                while (__all((int)(v >= target)) == 0) {
                    __builtin_amdgcn_s_sleep(1);
                    v = __hip_atomic_load(bar + tid, __ATOMIC_RELAXED,
                                          __HIP_MEMORY_SCOPE_AGENT);
                }
                asm volatile("" ::: "memory");
            }
            __syncthreads();
        }
    }
}

// ---------------- broadcast h over the 40 identical batch rows ----------------
__global__ __launch_bounds__(256) void bcast_out(const float* __restrict__ hs_c,
                                                 float* __restrict__ out) {
    const int gi = blockIdx.x * 256 + threadIdx.x;   // float4 index; total 655360
    const int t = gi / (BATCH * (H_DIM / 4));
    const int rem = gi - t * (BATCH * (H_DIM / 4));
    const int jq = rem & (H_DIM / 4 - 1);
    const float4 v = ((const float4*)hs_c)[t * (H_DIM / 4) + jq];
    ((float4*)out)[gi] = v;
}

extern "C" void kernel_launch(void* const* d_in, const int* in_sizes, int n_in,
                              void* d_out, int out_size, void* d_ws, size_t ws_size,
                              hipStream_t stream) {
    const float* features = (const float*)d_in[0];
    const float* w_ih     = (const float*)d_in[1];
    const float* w_hh     = (const float*)d_in[2];
    const float* b_ih     = (const float*)d_in[3];
    const float* b_hh     = (const float*)d_in[4];
    float* out = (float*)d_out;
    float* ws  = (float*)d_ws;

    unsigned* bar  = (unsigned*)d_ws;
    unsigned* a_hi = (unsigned*)(ws + OFF_AH);
    unsigned* a_lo = (unsigned*)(ws + OFF_AL);
    float* xw   = ws + OFF_XW;
    float* hs_c = ws + OFF_HS;
    float* part = ws + OFF_PART;

    int KS = 8;
    while (KS > 1 && (OFF_PART + (size_t)KS * SEQ * G4) * 4 > ws_size) KS >>= 1;
    const int kspan = IN_DIM / KS;

    zero_bar<<<1, 256, 0, stream>>>(bar);
    convert_a<<<(SEQ * IN_DIM / 4) / 256, 256, 0, stream>>>(features, a_hi, a_lo);
    gemm_mfma<<<dim3(G4 / 64, KS), 256, 0, stream>>>(w_ih, a_hi, a_lo, part, kspan);
    reduce_xw<<<(SEQ * G4) / 256, 256, 0, stream>>>(part, b_ih, b_hh, xw, KS);
    lstm_scan<<<NB_SCAN, NT_SCAN, 0, stream>>>(xw, w_hh, hs_c, bar);
    bcast_out<<<(SEQ * BATCH * H_DIM / 4) / 256, 256, 0, stream>>>(hs_c, out);
}

// Round 5
// 633.962 us; speedup vs baseline: 1.1650x; 1.1650x over previous
//
#include <hip/hip_runtime.h>
#include <hip/hip_bf16.h>
#include <math.h>

#define SEQ 64
#define IN_DIM 16384
#define H_DIM 1024
#define G4 4096   // 4*H
#define BATCH 40
#define NB_SCAN 64
#define NT_SCAN 1024
#define POISON 0xAAAAAAAAu
#define H_BIAS 2.0f

typedef short bf16x8 __attribute__((ext_vector_type(8)));   // 8 bf16 bit-patterns (4 VGPRs)
typedef float f32x4 __attribute__((ext_vector_type(4)));
typedef unsigned int uvec4 __attribute__((ext_vector_type(4)));
typedef unsigned int uvec2 __attribute__((ext_vector_type(2)));

// ---------------- ws layout (floats) ----------------
// [0 .. 256)      (unused; kept for layout stability)
// OFF_AH          a_hi : [64][16384] bf16 bits (512K float slots)
// OFF_AL          a_lo : [64][16384] bf16 bits
// OFF_XW          xw   : [64][4096]
// OFF_HS          hs_c : [64][1024]  (write-once h exchange; values stored as h+2.0)
// OFF_PART        part : [KS][64][4096]
#define OFF_AH   256
#define OFF_AL   (OFF_AH + (size_t)SEQ * IN_DIM / 2)
#define OFF_XW   (OFF_AL + (size_t)SEQ * IN_DIM / 2)
#define OFF_HS   (OFF_XW + (size_t)SEQ * G4)
#define OFF_PART (OFF_HS + (size_t)SEQ * H_DIM)

// ---------------- explicit poison of the h-exchange buffer ----------------
// (belt+suspenders: harness poisons d_ws to 0xAA, but we don't rely on it)
__global__ __launch_bounds__(256) void poison_hs(unsigned* __restrict__ hs) {
    const int i = blockIdx.x * 256 + threadIdx.x;   // uvec4 index; 16384 total
    uvec4 p; p.x = POISON; p.y = POISON; p.z = POISON; p.w = POISON;
    ((uvec4*)hs)[i] = p;
}

// ---------------- features fp32 -> bf16 hi/lo (lo = exact residual) ----------------
__global__ __launch_bounds__(256) void convert_a(const float* __restrict__ f,
                                                 unsigned* __restrict__ a_hi,
                                                 unsigned* __restrict__ a_lo) {
    const int i = blockIdx.x * 256 + threadIdx.x;          // float4 index
    uvec4 u = ((const uvec4*)f)[i];
    unsigned h0 = (u.x >> 16) | (u.y & 0xffff0000u);
    unsigned h1 = (u.z >> 16) | (u.w & 0xffff0000u);
    float l0 = __uint_as_float(u.x) - __uint_as_float(u.x & 0xffff0000u);
    float l1 = __uint_as_float(u.y) - __uint_as_float(u.y & 0xffff0000u);
    float l2 = __uint_as_float(u.z) - __uint_as_float(u.z & 0xffff0000u);
    float l3 = __uint_as_float(u.w) - __uint_as_float(u.w & 0xffff0000u);
    unsigned q0 = (__float_as_uint(l0) >> 16) | (__float_as_uint(l1) & 0xffff0000u);
    unsigned q1 = (__float_as_uint(l2) >> 16) | (__float_as_uint(l3) & 0xffff0000u);
    uvec2 hv; hv.x = h0; hv.y = h1;
    uvec2 lv; lv.x = q0; lv.y = q1;
    ((uvec2*)a_hi)[i] = hv;
    ((uvec2*)a_lo)[i] = lv;
}

// ---------------- split-bf16 MFMA GEMM: part[kz][t][j] = sum_k A[t][k]*w_ih[j][k] ----------------
// (unchanged from round 3/4 — kept byte-identical for attribution)
__global__ __launch_bounds__(256, 2) void gemm_mfma(const float* __restrict__ w_ih,
                                                    const unsigned* __restrict__ a_hi,
                                                    const unsigned* __restrict__ a_lo,
                                                    float* __restrict__ part, int kspan) {
    const int tid = threadIdx.x;
    const int wv   = tid >> 6;
    const int lane = tid & 63;
    const int col  = lane & 15;
    const int kg   = lane >> 4;
    const int jbase = blockIdx.x * 64 + wv * 16 + col;
    const int k0base = blockIdx.y * kspan;

    const float* wrow = w_ih + (size_t)jbase * IN_DIM;

    f32x4 acc[4] = {};   // t0 = 0,16,32,48

    for (int k0 = k0base; k0 < k0base + kspan; k0 += 32) {
        const int kf = k0 + kg * 8;
        uvec4 u0 = *(const uvec4*)(wrow + kf);
        uvec4 u1 = *(const uvec4*)(wrow + kf + 4);
        uvec4 hb, lb;
        hb.x = (u0.x >> 16) | (u0.y & 0xffff0000u);
        hb.y = (u0.z >> 16) | (u0.w & 0xffff0000u);
        hb.z = (u1.x >> 16) | (u1.y & 0xffff0000u);
        hb.w = (u1.z >> 16) | (u1.w & 0xffff0000u);
        float f0 = __uint_as_float(u0.x) - __uint_as_float(u0.x & 0xffff0000u);
        float f1 = __uint_as_float(u0.y) - __uint_as_float(u0.y & 0xffff0000u);
        float f2 = __uint_as_float(u0.z) - __uint_as_float(u0.z & 0xffff0000u);
        float f3 = __uint_as_float(u0.w) - __uint_as_float(u0.w & 0xffff0000u);
        float f4 = __uint_as_float(u1.x) - __uint_as_float(u1.x & 0xffff0000u);
        float f5 = __uint_as_float(u1.y) - __uint_as_float(u1.y & 0xffff0000u);
        float f6 = __uint_as_float(u1.z) - __uint_as_float(u1.z & 0xffff0000u);
        float f7 = __uint_as_float(u1.w) - __uint_as_float(u1.w & 0xffff0000u);
        lb.x = (__float_as_uint(f0) >> 16) | (__float_as_uint(f1) & 0xffff0000u);
        lb.y = (__float_as_uint(f2) >> 16) | (__float_as_uint(f3) & 0xffff0000u);
        lb.z = (__float_as_uint(f4) >> 16) | (__float_as_uint(f5) & 0xffff0000u);
        lb.w = (__float_as_uint(f6) >> 16) | (__float_as_uint(f7) & 0xffff0000u);
        bf16x8 bhi = __builtin_bit_cast(bf16x8, hb);
        bf16x8 blo = __builtin_bit_cast(bf16x8, lb);

#pragma unroll
        for (int i = 0; i < 4; ++i) {
            const size_t aidx = (size_t)(i * 16 + col) * (IN_DIM / 2) + (kf >> 1);  // u32 units
            uvec4 ah = *(const uvec4*)(a_hi + aidx);
            uvec4 al = *(const uvec4*)(a_lo + aidx);
            bf16x8 ahv = __builtin_bit_cast(bf16x8, ah);
            bf16x8 alv = __builtin_bit_cast(bf16x8, al);
            acc[i] = __builtin_amdgcn_mfma_f32_16x16x32_bf16(ahv, bhi, acc[i], 0, 0, 0);
            acc[i] = __builtin_amdgcn_mfma_f32_16x16x32_bf16(alv, bhi, acc[i], 0, 0, 0);
            acc[i] = __builtin_amdgcn_mfma_f32_16x16x32_bf16(ahv, blo, acc[i], 0, 0, 0);
        }
    }
    float* pb = part + (size_t)blockIdx.y * (SEQ * G4);
#pragma unroll
    for (int i = 0; i < 4; ++i)
#pragma unroll
        for (int r = 0; r < 4; ++r) {
            const int trow = i * 16 + kg * 4 + r;
            pb[(size_t)trow * G4 + jbase] = acc[i][r];
        }
}

// ---------------- reduce partials + bias -> xw ----------------
__global__ __launch_bounds__(256) void reduce_xw(const float* __restrict__ part,
                                                 const float* __restrict__ b_ih,
                                                 const float* __restrict__ b_hh,
                                                 float* __restrict__ xw, int KS) {
    const int idx = blockIdx.x * 256 + threadIdx.x;  // t*4096 + j
    const int j = idx & (G4 - 1);
    float s = b_ih[j] + b_hh[j];
    for (int ks = 0; ks < KS; ++ks) s += part[(size_t)ks * (SEQ * G4) + idx];
    xw[idx] = s;
}

// ---------------- persistent LSTM scan — BARRIER-FREE (data-flow sync) ----------------
// 64 blocks x 1024 thr. Block b owns h[b*16..b*16+16). hs_c slots are
// write-once, pre-poisoned 0xAAAAAAAA; h stored as h+2.0 in (1,3) — sign bit
// 0, so poison (sign bit 1) is deterministically distinguishable. Consumers
// poll their own word until non-poison: ONE MALL hop per step instead of
// store->vmcnt->flag->poll->load (three). Max inter-block skew = 1 step by
// the data DAG; no barrier, no flags, no waitcnt on the critical path.
__global__ __launch_bounds__(NT_SCAN, 1) void lstm_scan(const float* __restrict__ xw,
                                                        const float* __restrict__ w_hh,
                                                        float* __restrict__ hs_c) {
    const int tid = threadIdx.x;
    const int b = blockIdx.x;
    const int r = tid & 63;      // gate-row 0..63
    const int q = tid >> 6;      // k-chunk 0..15
    const int g = r >> 4;
    const int jl = r & 15;
    const size_t grow = (size_t)g * H_DIM + (size_t)b * 16 + jl;

    float4 w[16];
    {
        const float4* wp = (const float4*)(w_hh + grow * H_DIM + q * 64);
#pragma unroll
        for (int m = 0; m < 16; ++m) w[m] = wp[m];
    }
#pragma unroll
    for (int m = 0; m < 16; ++m)
        asm volatile("" : "+v"(w[m].x), "+v"(w[m].y), "+v"(w[m].z), "+v"(w[m].w));

    __shared__ float h_lds[H_DIM];
    __shared__ float red[64][17];
    __shared__ float gate_lds[64];
    __shared__ float h_own[16];

    const unsigned* hs_u = (const unsigned*)hs_c;
    const int my_src = tid >> 4;          // producer block of h slot `tid`

    float c_reg = 0.f;   // live on tid<16

    for (int t = 0; t < SEQ; ++t) {
        float xwv = 0.f;
        if (tid < 64)  // prefetch gate bias row (no h dependency)
            xwv = xw[(size_t)t * G4 + (size_t)(tid >> 4) * H_DIM + b * 16 + (tid & 15)];
        float acc = 0.f;
        if (t > 0) {
            // stage h(t-1): own block's slice from LDS, rest by poison-polling MALL
            if (my_src == b) {
                h_lds[tid] = h_own[tid & 15];
            } else {
                unsigned v = __hip_atomic_load(hs_u + (size_t)(t - 1) * H_DIM + tid,
                                               __ATOMIC_RELAXED, __HIP_MEMORY_SCOPE_AGENT);
                while (v == POISON) {
                    v = __hip_atomic_load(hs_u + (size_t)(t - 1) * H_DIM + tid,
                                          __ATOMIC_RELAXED, __HIP_MEMORY_SCOPE_AGENT);
                }
                h_lds[tid] = __uint_as_float(v) - H_BIAS;
            }
            __syncthreads();
#pragma unroll
            for (int m = 0; m < 16; ++m) {
                float4 h4 = *(const float4*)&h_lds[q * 64 + m * 4];  // wave-uniform -> broadcast
                acc += w[m].x * h4.x + w[m].y * h4.y + w[m].z * h4.z + w[m].w * h4.w;
            }
        }
        red[r][q] = acc;
        __syncthreads();
        if (tid < 64) {
            float s = 0.f;
#pragma unroll
            for (int qq = 0; qq < 16; ++qq) s += red[tid][qq];
            gate_lds[tid] = xwv + s;
        }
        __syncthreads();
        if (tid < 16) {
            float iv = gate_lds[tid];
            float fv = gate_lds[16 + tid];
            float gv = gate_lds[32 + tid];
            float ov = gate_lds[48 + tid];
            iv = 1.f / (1.f + expf(-iv));
            fv = 1.f / (1.f + expf(-fv));
            gv = tanhf(gv);
            ov = 1.f / (1.f + expf(-ov));
            c_reg = fv * c_reg + iv * gv;
            float hv = ov * tanhf(c_reg);
            h_own[tid] = hv;                                         // fast path for own block
            __hip_atomic_store(hs_c + (size_t)t * H_DIM + b * 16 + tid, hv + H_BIAS,
                               __ATOMIC_RELAXED, __HIP_MEMORY_SCOPE_AGENT);
        }
        __syncthreads();   // h_own visible to next iteration's stagers
    }
}

// ---------------- broadcast h over the 40 identical batch rows (undo +2 bias) ----------------
__global__ __launch_bounds__(256) void bcast_out(const float* __restrict__ hs_c,
                                                 float* __restrict__ out) {
    const int gi = blockIdx.x * 256 + threadIdx.x;   // float4 index; total 655360
    const int t = gi / (BATCH * (H_DIM / 4));
    const int rem = gi - t * (BATCH * (H_DIM / 4));
    const int jq = rem & (H_DIM / 4 - 1);
    float4 v = ((const float4*)hs_c)[t * (H_DIM / 4) + jq];
    v.x -= H_BIAS; v.y -= H_BIAS; v.z -= H_BIAS; v.w -= H_BIAS;
    ((float4*)out)[gi] = v;
}

extern "C" void kernel_launch(void* const* d_in, const int* in_sizes, int n_in,
                              void* d_out, int out_size, void* d_ws, size_t ws_size,
                              hipStream_t stream) {
    const float* features = (const float*)d_in[0];
    const float* w_ih     = (const float*)d_in[1];
    const float* w_hh     = (const float*)d_in[2];
    const float* b_ih     = (const float*)d_in[3];
    const float* b_hh     = (const float*)d_in[4];
    float* out = (float*)d_out;
    float* ws  = (float*)d_ws;

    unsigned* a_hi = (unsigned*)(ws + OFF_AH);
    unsigned* a_lo = (unsigned*)(ws + OFF_AL);
    float* xw   = ws + OFF_XW;
    float* hs_c = ws + OFF_HS;
    float* part = ws + OFF_PART;

    int KS = 8;
    while (KS > 1 && (OFF_PART + (size_t)KS * SEQ * G4) * 4 > ws_size) KS >>= 1;
    const int kspan = IN_DIM / KS;

    poison_hs<<<(SEQ * H_DIM / 4) / 256, 256, 0, stream>>>((unsigned*)hs_c);
    convert_a<<<(SEQ * IN_DIM / 4) / 256, 256, 0, stream>>>(features, a_hi, a_lo);
    gemm_mfma<<<dim3(G4 / 64, KS), 256, 0, stream>>>(w_ih, a_hi, a_lo, part, kspan);
    reduce_xw<<<(SEQ * G4) / 256, 256, 0, stream>>>(part, b_ih, b_hh, xw, KS);
    lstm_scan<<<NB_SCAN, NT_SCAN, 0, stream>>>(xw, w_hh, hs_c);
    bcast_out<<<(SEQ * BATCH * H_DIM / 4) / 256, 256, 0, stream>>>(hs_c, out);
}